// Round 5
// baseline (2586.682 us; speedup 1.0000x reference)
//
#include <hip/hip_runtime.h>
#include <hip/hip_bf16.h>

typedef unsigned short u16b;
typedef __attribute__((ext_vector_type(8))) short bf16x8;
typedef __attribute__((ext_vector_type(4))) float f32x4;

__device__ __forceinline__ float b2f(u16b u) { return __uint_as_float(((unsigned)u) << 16); }
__device__ __forceinline__ u16b f2b(float f) {
    unsigned u = __float_as_uint(f);
    unsigned r = u + 0x7fffu + ((u >> 16) & 1u);
    return (u16b)(r >> 16);
}
__device__ __forceinline__ int pk2(float a, float b) {
    return (int)f2b(a) | ((int)f2b(b) << 16);
}
// unpack packed-int (two bf16) -> two floats
__device__ __forceinline__ void up2(int p, float& a, float& b) {
    a = __uint_as_float(((unsigned)p) << 16);
    b = __uint_as_float(((unsigned)p) & 0xffff0000u);
}

// async 16B global -> LDS (dest = wave-uniform base + lane*16)
__device__ __forceinline__ void async16(const u16b* g, u16b* l) {
    __builtin_amdgcn_global_load_lds(
        (const __attribute__((address_space(1))) unsigned int*)g,
        (__attribute__((address_space(3))) unsigned int*)l,
        16, 0, 0);
}

#define BATCH 4096
#define NPROJ 1920   /* proj out stride; cols 0..1799 valid */

// ================= weight packs (f32 -> bf16 transposed, zero-pad K->Kp, N->Npad) =================
__global__ void pack_wcatT(const float* __restrict__ WQ, const float* __restrict__ WK,
                           const float* __restrict__ WV, const float* __restrict__ WQ2,
                           const float* __restrict__ WK2, const float* __restrict__ WV2,
                           u16b* __restrict__ Wt) {   // [1920][320]
    int idx = blockIdx.x * 256 + threadIdx.x;
    if (idx >= 1920 * 320) return;
    int n = idx / 320, k = idx % 320;
    float v = 0.0f;
    if (k < 300 && n < 1800) {
        if      (n < 400)  v = WQ [k * 400 + n];
        else if (n < 800)  v = WK [k * 400 + (n - 400)];
        else if (n < 1200) v = WV [k * 400 + (n - 800)];
        else if (n < 1400) v = WQ2[k * 200 + (n - 1200)];
        else if (n < 1600) v = WK2[k * 200 + (n - 1400)];
        else               v = WV2[k * 200 + (n - 1600)];
    }
    Wt[idx] = f2b(v);
}

__global__ void pack_wt(const float* __restrict__ W, u16b* __restrict__ Wt,
                        int K, int N, int Kp, int Npad) {
    int idx = blockIdx.x * 256 + threadIdx.x;
    if (idx >= Npad * Kp) return;
    int n = idx / Kp, k = idx % Kp;
    Wt[idx] = f2b((k < K && n < N) ? W[k * N + n] : 0.0f);
}

// vert columns of Acat: Acat[b][800+c] = bf16(vert_table[vids[b]][c]), c in [0,224) (pad 200..223 = 0)
__global__ void pack_vert(const int* __restrict__ vids, const float* __restrict__ vtab,
                          u16b* __restrict__ Acat) {
    int idx = blockIdx.x * 256 + threadIdx.x;
    if (idx >= BATCH * 224) return;
    int b = idx / 224, c = idx % 224;
    u16b v = 0;
    if (c < 200) v = f2b(vtab[(long long)vids[b] * 200 + c]);
    Acat[(long long)b * 1024 + 800 + c] = v;
}

// ================= gather + f32->bf16 convert: Abuf[M][320] = table[ids[m]][0..299] =================
__global__ void gather_bf16(const int* __restrict__ ids, const float* __restrict__ table,
                            u16b* __restrict__ Abuf, int nrows) {
    int idx = blockIdx.x * 256 + threadIdx.x;
    if (idx >= nrows * 40) return;
    int row = idx / 40, c = idx % 40;
    int k = c * 8;
    const float* src = table + (long long)ids[row] * 300;
    int4 v;
    if (k + 8 <= 300) {
        float4 f0 = *(const float4*)(src + k);
        float4 f1 = *(const float4*)(src + k + 4);
        v.x = pk2(f0.x, f0.y); v.y = pk2(f0.z, f0.w);
        v.z = pk2(f1.x, f1.y); v.w = pk2(f1.z, f1.w);
    } else if (k < 300) {
        float f[8];
        #pragma unroll
        for (int i = 0; i < 8; i++) f[i] = (k + i < 300) ? src[k + i] : 0.0f;
        v.x = pk2(f[0], f[1]); v.y = pk2(f[2], f[3]);
        v.z = pk2(f[4], f[5]); v.w = pk2(f[6], f[7]);
    } else {
        v.x = v.y = v.z = v.w = 0;
    }
    *(int4*)(Abuf + (long long)row * 320 + k) = v;
}

// ================= MFMA GEMM, m97-style =================
// Out[M,N] = A[M,lda](bf16) @ Wt[Npad][ldwt]^T + bias (opt tanh); out bf16 or f32.
// M%128==0; Wt zero-padded in K and N; grid=(ceil(N/128), M/128); 256 thr = 4 waves.
template<int HAS_BIAS, int DO_TANH, int F32OUT>
__global__ __launch_bounds__(256) void gemm_mfma2(
        const u16b* __restrict__ A, long long lda,
        const u16b* __restrict__ Wt, int ldwt,
        const float* __restrict__ Bias,
        void* __restrict__ OutV, long long ldo,
        int kiters, int N) {
    __shared__ __align__(16) u16b As[128 * 32];
    __shared__ __align__(16) u16b Bs[128 * 32];
    const int t = threadIdx.x, lane = t & 63, w = t >> 6;
    const int wm = w & 1, wn = w >> 1;
    const long long m0 = (long long)blockIdx.y * 128;
    const int n0 = blockIdx.x * 128;

    const int r0 = w * 32 + (lane >> 2);
    const int r1 = r0 + 16;
    const int cch = ((lane & 3) ^ ((r0 >> 1) & 3)) * 8;
    const u16b* gA0 = A + (m0 + r0) * lda + cch;
    const u16b* gA1 = A + (m0 + r1) * lda + cch;
    const u16b* gB0 = Wt + (long long)(n0 + r0) * ldwt + cch;
    const u16b* gB1 = Wt + (long long)(n0 + r1) * ldwt + cch;
    u16b* lA0 = &As[(w * 32) * 32];
    u16b* lA1 = &As[(w * 32 + 16) * 32];
    u16b* lB0 = &Bs[(w * 32) * 32];
    u16b* lB1 = &Bs[(w * 32 + 16) * 32];

    const int lr = lane & 15;
    const int kq8 = lane >> 4;
    const int slot = (kq8 ^ ((lr >> 1) & 3)) * 8;
    const u16b* aBase = &As[(wm * 64 + lr) * 32 + slot];
    const u16b* bBase = &Bs[(wn * 64 + lr) * 32 + slot];

    f32x4 acc[4][4];
    const f32x4 zf = {0.f, 0.f, 0.f, 0.f};
    #pragma unroll
    for (int mi = 0; mi < 4; mi++)
        #pragma unroll
        for (int ni = 0; ni < 4; ni++) acc[mi][ni] = zf;

    for (int it = 0; it < kiters; ++it) {
        async16(gA0, lA0); async16(gA1, lA1);
        async16(gB0, lB0); async16(gB1, lB1);
        gA0 += 32; gA1 += 32; gB0 += 32; gB1 += 32;
        __syncthreads();
        bf16x8 af[4], bf[4];
        #pragma unroll
        for (int mi = 0; mi < 4; mi++) af[mi] = *(const bf16x8*)(aBase + mi * 16 * 32);
        #pragma unroll
        for (int ni = 0; ni < 4; ni++) bf[ni] = *(const bf16x8*)(bBase + ni * 16 * 32);
        #pragma unroll
        for (int mi = 0; mi < 4; mi++)
            #pragma unroll
            for (int ni = 0; ni < 4; ni++)
                acc[mi][ni] = __builtin_amdgcn_mfma_f32_16x16x32_bf16(af[mi], bf[ni], acc[mi][ni], 0, 0, 0);
        __syncthreads();
    }

    const int cl = lane & 15;
    const int rb = (lane >> 4) * 4;
    #pragma unroll
    for (int ni = 0; ni < 4; ni++) {
        const int col = n0 + wn * 64 + ni * 16 + cl;
        if (col >= N) continue;
        const float bias = HAS_BIAS ? Bias[col] : 0.0f;
        #pragma unroll
        for (int mi = 0; mi < 4; mi++) {
            #pragma unroll
            for (int r = 0; r < 4; r++) {
                const long long row = m0 + wm * 64 + mi * 16 + rb + r;
                float v = acc[mi][ni][r] + bias;
                if (DO_TANH) v = tanhf(v);
                if (F32OUT) ((float*)OutV)[row * ldo + col] = v;
                else        ((u16b*)OutV)[row * ldo + col] = f2b(v);
            }
        }
    }
}

// ---------------- title attention: self MHA(20,20) + co MHA(5,40) -> Tcat[C,30,608] ----------------
// Tproj row: [Q1:0..399 | K1:400..799 | V1:800..1199 | Q2:1200..1399 | K2:1400..1599 | V2:1600..1799]
__global__ __launch_bounds__(256) void attn_title(const u16b* __restrict__ Tproj,
                                                  const u16b* __restrict__ Eproj,
                                                  u16b* __restrict__ Tcat) {
    __shared__ __align__(16) u16b sm[24000];  // ph1: K1 30x400 @0, V1 @12000; ph2: K2 10x200 @0, V2 @2000
    const int b = blockIdx.x, t = threadIdx.x;
    const u16b* baseT = Tproj + (long long)b * 30 * NPROJ;
    // ---- phase 1 staging (int4): K1, V1
    for (int c = t; c < 3000; c += 256) {
        int half = c / 1500, cc = c % 1500;
        int row = cc / 50, off = (cc % 50) * 8;
        int4 v = *(const int4*)(baseT + (long long)row * NPROJ + (half ? 800 : 400) + off);
        *(int4*)(&sm[half * 12000 + row * 400 + off]) = v;
    }
    __syncthreads();
    const float scale1 = 0.22360679774997896f;  // 1/sqrt(20)
    for (int rh = t; rh < 600; rh += 256) {
        int h = rh / 30, i = rh % 30;
        const u16b* qp = baseT + (long long)i * NPROJ + h * 20;
        float q[20];
        #pragma unroll
        for (int u = 0; u < 5; u++) {
            int2 pp = *(const int2*)(qp + u * 4);
            up2(pp.x, q[u*4+0], q[u*4+1]); up2(pp.y, q[u*4+2], q[u*4+3]);
        }
        float s[30]; float mx = -1e30f;
        #pragma unroll
        for (int j = 0; j < 30; j++) {
            const u16b* kp = &sm[j * 400 + h * 20];
            float a = 0.0f;
            #pragma unroll
            for (int u = 0; u < 5; u++) {
                int2 pp = *(const int2*)(kp + u * 4);
                float x0,x1,x2,x3; up2(pp.x,x0,x1); up2(pp.y,x2,x3);
                a += q[u*4]*x0 + q[u*4+1]*x1 + q[u*4+2]*x2 + q[u*4+3]*x3;
            }
            s[j] = a * scale1; mx = fmaxf(mx, s[j]);
        }
        float sum = 0.0f;
        #pragma unroll
        for (int j = 0; j < 30; j++) { s[j] = __expf(s[j] - mx); sum += s[j]; }
        float inv = 1.0f / sum;
        #pragma unroll
        for (int j = 0; j < 30; j++) s[j] *= inv;
        float o[20] = {};
        #pragma unroll
        for (int j = 0; j < 30; j++) {
            const u16b* vp = &sm[12000 + j * 400 + h * 20];
            float sj = s[j];
            #pragma unroll
            for (int u = 0; u < 5; u++) {
                int2 pp = *(const int2*)(vp + u * 4);
                float x0,x1,x2,x3; up2(pp.x,x0,x1); up2(pp.y,x2,x3);
                o[u*4]   = fmaf(sj, x0, o[u*4]);
                o[u*4+1] = fmaf(sj, x1, o[u*4+1]);
                o[u*4+2] = fmaf(sj, x2, o[u*4+2]);
                o[u*4+3] = fmaf(sj, x3, o[u*4+3]);
            }
        }
        u16b* op = Tcat + (long long)(b * 30 + i) * 608 + h * 20;
        #pragma unroll
        for (int u = 0; u < 10; u++) *(int*)(op + u * 2) = pk2(o[u*2], o[u*2+1]);
    }
    __syncthreads();
    // ---- phase 2 staging: K2 (10x200) @0, V2 @2000 from Eproj
    const u16b* baseE = Eproj + (long long)b * 10 * NPROJ;
    for (int c = t; c < 500; c += 256) {
        int half = c / 250, cc = c % 250;
        int row = cc / 25, off = (cc % 25) * 8;
        int4 v = *(const int4*)(baseE + (long long)row * NPROJ + (half ? 1600 : 1400) + off);
        *(int4*)(&sm[half * 2000 + row * 200 + off]) = v;
    }
    __syncthreads();
    const float scale2 = 0.15811388300841897f;  // 1/sqrt(40)
    if (t < 150) {
        int h = t / 30, i = t % 30;
        const u16b* qp = baseT + (long long)i * NPROJ + 1200 + h * 40;
        float q[40];
        #pragma unroll
        for (int u = 0; u < 10; u++) {
            int2 pp = *(const int2*)(qp + u * 4);
            up2(pp.x, q[u*4+0], q[u*4+1]); up2(pp.y, q[u*4+2], q[u*4+3]);
        }
        float s[10]; float mx = -1e30f;
        #pragma unroll
        for (int j = 0; j < 10; j++) {
            const u16b* kp = &sm[j * 200 + h * 40];
            float a = 0.0f;
            #pragma unroll
            for (int u = 0; u < 5; u++) {
                int4 pp = *(const int4*)(kp + u * 8);
                float x0,x1,x2,x3,x4,x5,x6,x7;
                up2(pp.x,x0,x1); up2(pp.y,x2,x3); up2(pp.z,x4,x5); up2(pp.w,x6,x7);
                a += q[u*8]*x0 + q[u*8+1]*x1 + q[u*8+2]*x2 + q[u*8+3]*x3
                   + q[u*8+4]*x4 + q[u*8+5]*x5 + q[u*8+6]*x6 + q[u*8+7]*x7;
            }
            s[j] = a * scale2; mx = fmaxf(mx, s[j]);
        }
        float sum = 0.0f;
        #pragma unroll
        for (int j = 0; j < 10; j++) { s[j] = __expf(s[j] - mx); sum += s[j]; }
        float inv = 1.0f / sum;
        #pragma unroll
        for (int j = 0; j < 10; j++) s[j] *= inv;
        float o[40] = {};
        #pragma unroll
        for (int j = 0; j < 10; j++) {
            const u16b* vp = &sm[2000 + j * 200 + h * 40];
            float sj = s[j];
            #pragma unroll
            for (int u = 0; u < 5; u++) {
                int4 pp = *(const int4*)(vp + u * 8);
                float x0,x1,x2,x3,x4,x5,x6,x7;
                up2(pp.x,x0,x1); up2(pp.y,x2,x3); up2(pp.z,x4,x5); up2(pp.w,x6,x7);
                o[u*8]   = fmaf(sj, x0, o[u*8]);   o[u*8+1] = fmaf(sj, x1, o[u*8+1]);
                o[u*8+2] = fmaf(sj, x2, o[u*8+2]); o[u*8+3] = fmaf(sj, x3, o[u*8+3]);
                o[u*8+4] = fmaf(sj, x4, o[u*8+4]); o[u*8+5] = fmaf(sj, x5, o[u*8+5]);
                o[u*8+6] = fmaf(sj, x6, o[u*8+6]); o[u*8+7] = fmaf(sj, x7, o[u*8+7]);
            }
        }
        u16b* op = Tcat + (long long)(b * 30 + i) * 608 + 400 + h * 40;
        #pragma unroll
        for (int u = 0; u < 20; u++) *(int*)(op + u * 2) = pk2(o[u*2], o[u*2+1]);
    }
}

// ---------------- entity attention -> Ecat[C,10,608] ----------------
__global__ __launch_bounds__(256) void attn_entity(const u16b* __restrict__ Tproj,
                                                   const u16b* __restrict__ Eproj,
                                                   u16b* __restrict__ Ecat) {
    __shared__ __align__(16) u16b sm[12000];  // ph1: K1 10x400 @0, V1 @4000; ph2: K2 30x200 @0, V2 @6000
    const int b = blockIdx.x, t = threadIdx.x;
    const u16b* baseE = Eproj + (long long)b * 10 * NPROJ;
    const u16b* baseT = Tproj + (long long)b * 30 * NPROJ;
    // ---- phase 1 staging
    for (int c = t; c < 1000; c += 256) {
        int half = c / 500, cc = c % 500;
        int row = cc / 50, off = (cc % 50) * 8;
        int4 v = *(const int4*)(baseE + (long long)row * NPROJ + (half ? 800 : 400) + off);
        *(int4*)(&sm[half * 4000 + row * 400 + off]) = v;
    }
    __syncthreads();
    const float scale1 = 0.22360679774997896f;
    if (t < 200) {
        int h = t / 10, i = t % 10;
        const u16b* qp = baseE + (long long)i * NPROJ + h * 20;
        float q[20];
        #pragma unroll
        for (int u = 0; u < 5; u++) {
            int2 pp = *(const int2*)(qp + u * 4);
            up2(pp.x, q[u*4+0], q[u*4+1]); up2(pp.y, q[u*4+2], q[u*4+3]);
        }
        float s[10]; float mx = -1e30f;
        #pragma unroll
        for (int j = 0; j < 10; j++) {
            const u16b* kp = &sm[j * 400 + h * 20];
            float a = 0.0f;
            #pragma unroll
            for (int u = 0; u < 5; u++) {
                int2 pp = *(const int2*)(kp + u * 4);
                float x0,x1,x2,x3; up2(pp.x,x0,x1); up2(pp.y,x2,x3);
                a += q[u*4]*x0 + q[u*4+1]*x1 + q[u*4+2]*x2 + q[u*4+3]*x3;
            }
            s[j] = a * scale1; mx = fmaxf(mx, s[j]);
        }
        float sum = 0.0f;
        #pragma unroll
        for (int j = 0; j < 10; j++) { s[j] = __expf(s[j] - mx); sum += s[j]; }
        float inv = 1.0f / sum;
        #pragma unroll
        for (int j = 0; j < 10; j++) s[j] *= inv;
        float o[20] = {};
        #pragma unroll
        for (int j = 0; j < 10; j++) {
            const u16b* vp = &sm[4000 + j * 400 + h * 20];
            float sj = s[j];
            #pragma unroll
            for (int u = 0; u < 5; u++) {
                int2 pp = *(const int2*)(vp + u * 4);
                float x0,x1,x2,x3; up2(pp.x,x0,x1); up2(pp.y,x2,x3);
                o[u*4]   = fmaf(sj, x0, o[u*4]);   o[u*4+1] = fmaf(sj, x1, o[u*4+1]);
                o[u*4+2] = fmaf(sj, x2, o[u*4+2]); o[u*4+3] = fmaf(sj, x3, o[u*4+3]);
            }
        }
        u16b* op = Ecat + (long long)(b * 10 + i) * 608 + h * 20;
        #pragma unroll
        for (int u = 0; u < 10; u++) *(int*)(op + u * 2) = pk2(o[u*2], o[u*2+1]);
    }
    __syncthreads();
    // ---- phase 2 staging: K2 (30x200) @0, V2 @6000 from Tproj
    for (int c = t; c < 1500; c += 256) {
        int half = c / 750, cc = c % 750;
        int row = cc / 25, off = (cc % 25) * 8;
        int4 v = *(const int4*)(baseT + (long long)row * NPROJ + (half ? 1600 : 1400) + off);
        *(int4*)(&sm[half * 6000 + row * 200 + off]) = v;
    }
    __syncthreads();
    const float scale2 = 0.15811388300841897f;
    if (t < 50) {
        int h = t / 10, i = t % 10;
        const u16b* qp = baseE + (long long)i * NPROJ + 1200 + h * 40;
        float q[40];
        #pragma unroll
        for (int u = 0; u < 10; u++) {
            int2 pp = *(const int2*)(qp + u * 4);
            up2(pp.x, q[u*4+0], q[u*4+1]); up2(pp.y, q[u*4+2], q[u*4+3]);
        }
        float s[30]; float mx = -1e30f;
        #pragma unroll
        for (int j = 0; j < 30; j++) {
            const u16b* kp = &sm[j * 200 + h * 40];
            float a = 0.0f;
            #pragma unroll
            for (int u = 0; u < 5; u++) {
                int4 pp = *(const int4*)(kp + u * 8);
                float x0,x1,x2,x3,x4,x5,x6,x7;
                up2(pp.x,x0,x1); up2(pp.y,x2,x3); up2(pp.z,x4,x5); up2(pp.w,x6,x7);
                a += q[u*8]*x0 + q[u*8+1]*x1 + q[u*8+2]*x2 + q[u*8+3]*x3
                   + q[u*8+4]*x4 + q[u*8+5]*x5 + q[u*8+6]*x6 + q[u*8+7]*x7;
            }
            s[j] = a * scale2; mx = fmaxf(mx, s[j]);
        }
        float sum = 0.0f;
        #pragma unroll
        for (int j = 0; j < 30; j++) { s[j] = __expf(s[j] - mx); sum += s[j]; }
        float inv = 1.0f / sum;
        #pragma unroll
        for (int j = 0; j < 30; j++) s[j] *= inv;
        float o[40] = {};
        #pragma unroll
        for (int j = 0; j < 30; j++) {
            const u16b* vp = &sm[6000 + j * 200 + h * 40];
            float sj = s[j];
            #pragma unroll
            for (int u = 0; u < 5; u++) {
                int4 pp = *(const int4*)(vp + u * 8);
                float x0,x1,x2,x3,x4,x5,x6,x7;
                up2(pp.x,x0,x1); up2(pp.y,x2,x3); up2(pp.z,x4,x5); up2(pp.w,x6,x7);
                o[u*8]   = fmaf(sj, x0, o[u*8]);   o[u*8+1] = fmaf(sj, x1, o[u*8+1]);
                o[u*8+2] = fmaf(sj, x2, o[u*8+2]); o[u*8+3] = fmaf(sj, x3, o[u*8+3]);
                o[u*8+4] = fmaf(sj, x4, o[u*8+4]); o[u*8+5] = fmaf(sj, x5, o[u*8+5]);
                o[u*8+6] = fmaf(sj, x6, o[u*8+6]); o[u*8+7] = fmaf(sj, x7, o[u*8+7]);
            }
        }
        u16b* op = Ecat + (long long)(b * 10 + i) * 608 + 400 + h * 40;
        #pragma unroll
        for (int u = 0; u < 20; u++) *(int*)(op + u * 2) = pk2(o[u*2], o[u*2+1]);
    }
}

// ---------------- attention pooling finalize -> bf16 into Acat (stride 1024) ----------------
template <int L>
__global__ __launch_bounds__(256) void pool_finalize(const u16b* __restrict__ P,
                                                     const u16b* __restrict__ Vv,
                                                     const float* __restrict__ w2,
                                                     u16b* __restrict__ outv) {
    __shared__ float sred[L][8];
    __shared__ float sa[L];
    const int b = blockIdx.x, t = threadIdx.x;
    const int i = t / 8, u = t % 8;
    if (i < L) {
        float p = 0.0f;
        const u16b* Pr = P + (long long)(b * L + i) * 200 + u * 25;
        const float* wr = w2 + u * 25;
        #pragma unroll
        for (int c = 0; c < 25; c++) p += b2f(Pr[c]) * wr[c];
        sred[i][u] = p;
    }
    __syncthreads();
    if (t == 0) {
        float s[L];
        float mx = -1e30f;
        for (int ii = 0; ii < L; ii++) {
            float v = 0.0f;
            for (int uu = 0; uu < 8; uu++) v += sred[ii][uu];
            s[ii] = v;
            mx = fmaxf(mx, v);
        }
        float sum = 0.0f;
        for (int ii = 0; ii < L; ii++) { s[ii] = __expf(s[ii] - mx); sum += s[ii]; }
        float inv = 1.0f / sum;
        for (int ii = 0; ii < L; ii++) sa[ii] = s[ii] * inv;
    }
    __syncthreads();
    for (int f = t; f < 400; f += 256) {
        float o = 0.0f;
        #pragma unroll
        for (int ii = 0; ii < L; ii++) o += sa[ii] * b2f(Vv[(long long)(b * L + ii) * 400 + f]);
        outv[(long long)b * 1024 + f] = f2b(o);
    }
}

extern "C" void kernel_launch(void* const* d_in, const int* in_sizes, int n_in,
                              void* d_out, int out_size, void* d_ws, size_t ws_size,
                              hipStream_t stream) {
    const int*   title_ids  = (const int*)d_in[0];
    const int*   vert_ids   = (const int*)d_in[1];
    const int*   entity_ids = (const int*)d_in[2];
    const float* word_table = (const float*)d_in[3];
    const float* vert_table = (const float*)d_in[4];
    const float* entity_table = (const float*)d_in[5];
    const float* WQ  = (const float*)d_in[6];
    const float* WK  = (const float*)d_in[7];
    const float* WV  = (const float*)d_in[8];
    const float* WQ2 = (const float*)d_in[9];
    const float* WK2 = (const float*)d_in[10];
    const float* WV2 = (const float*)d_in[11];
    const float* fc1_W = (const float*)d_in[12];
    const float* fc1_b = (const float*)d_in[13];
    const float* fc2_W = (const float*)d_in[14];
    const float* fc2_b = (const float*)d_in[15];
    const float* apt_W1 = (const float*)d_in[16];
    const float* apt_b1 = (const float*)d_in[17];
    const float* apt_w2 = (const float*)d_in[18];
    const float* ape_W1 = (const float*)d_in[19];
    const float* ape_b1 = (const float*)d_in[20];
    const float* ape_w2 = (const float*)d_in[21];
    const float* fc3_W = (const float*)d_in[22];
    const float* fc3_b = (const float*)d_in[23];

    // fixed region: packed bf16 weights + Acat (bf16 fc3 input, [4096][1024])
    const long long OFF_WCATT = 0;                               // 1920*320*2 = 1,228,800
    const long long OFF_FC1WT = 1228800ll;                       // 512*608*2  =   622,592
    const long long OFF_FC2WT = OFF_FC1WT + 622592ll;
    const long long OFF_APTWT = OFF_FC2WT + 622592ll;            // 256*416*2  =   212,992
    const long long OFF_APEWT = OFF_APTWT + 212992ll;
    const long long OFF_FC3WT = OFF_APEWT + 212992ll;            // 512*1024*2 = 1,048,576
    const long long OFF_ACAT  = OFF_FC3WT + 1048576ll;           // 4096*1024*2= 8,388,608
    const long long fixedB    = OFF_ACAT + 8388608ll;            // 12,337,152

    // per-chunk bytes: AbufT C*19200 + AbufE C*6400 + Tproj C*115200 + Eproj C*38400
    //                + Tcat C*36480 + Ecat C*12160 = C*227840
    int C = BATCH;
    while (C > 64 && fixedB + (long long)C * 227840ll > (long long)ws_size) C >>= 1;

    char* ws = (char*)d_ws;
    const long long OFF_ABUFT = fixedB;
    const long long OFF_ABUFE = OFF_ABUFT + (long long)C * 19200ll;
    const long long OFF_TPROJ = OFF_ABUFE + (long long)C * 6400ll;
    const long long OFF_EPROJ = OFF_TPROJ + (long long)C * 115200ll;
    const long long OFF_TCAT  = OFF_EPROJ + (long long)C * 38400ll;
    const long long OFF_ECAT  = OFF_TCAT  + (long long)C * 36480ll;
    // overlays (dead-region reuse within a chunk):
    const long long OFF_TV = OFF_ABUFT;
    const long long OFF_EV = OFF_ABUFT + (long long)C * 24000ll;
    const long long OFF_PT = OFF_EPROJ;
    const long long OFF_PE = OFF_EPROJ + (long long)C * 12000ll;

    u16b*  wcatT = (u16b*)(ws + OFF_WCATT);
    u16b*  fc1Wt = (u16b*)(ws + OFF_FC1WT);
    u16b*  fc2Wt = (u16b*)(ws + OFF_FC2WT);
    u16b*  aptWt = (u16b*)(ws + OFF_APTWT);
    u16b*  apeWt = (u16b*)(ws + OFF_APEWT);
    u16b*  fc3Wt = (u16b*)(ws + OFF_FC3WT);
    u16b*  Acat  = (u16b*)(ws + OFF_ACAT);
    u16b*  AbufT = (u16b*)(ws + OFF_ABUFT);
    u16b*  AbufE = (u16b*)(ws + OFF_ABUFE);
    u16b*  Tproj = (u16b*)(ws + OFF_TPROJ);
    u16b*  Eproj = (u16b*)(ws + OFF_EPROJ);
    u16b*  Tcat  = (u16b*)(ws + OFF_TCAT);
    u16b*  Ecat  = (u16b*)(ws + OFF_ECAT);
    u16b*  Tv    = (u16b*)(ws + OFF_TV);
    u16b*  Ev    = (u16b*)(ws + OFF_EV);
    u16b*  Pt    = (u16b*)(ws + OFF_PT);
    u16b*  Pe    = (u16b*)(ws + OFF_PE);

    // 1. pack bf16 transposed, zero-padded weights + vert columns of Acat
    pack_wcatT<<<(1920 * 320 + 255) / 256, 256, 0, stream>>>(WQ, WK, WV, WQ2, WK2, WV2, wcatT);
    pack_wt<<<(512 * 608 + 255) / 256, 256, 0, stream>>>(fc1_W, fc1Wt, 600, 400, 608, 512);
    pack_wt<<<(512 * 608 + 255) / 256, 256, 0, stream>>>(fc2_W, fc2Wt, 600, 400, 608, 512);
    pack_wt<<<(256 * 416 + 255) / 256, 256, 0, stream>>>(apt_W1, aptWt, 400, 200, 416, 256);
    pack_wt<<<(256 * 416 + 255) / 256, 256, 0, stream>>>(ape_W1, apeWt, 400, 200, 416, 256);
    pack_wt<<<(512 * 1024 + 255) / 256, 256, 0, stream>>>(fc3_W, fc3Wt, 1000, 400, 1024, 512);
    pack_vert<<<(BATCH * 224 + 255) / 256, 256, 0, stream>>>(vert_ids, vert_table, Acat);

    for (int c0 = 0; c0 < BATCH; c0 += C) {
        const int MT = C * 30, ME = C * 10;        // multiples of 128 (C%64==0)
        // 2a. gather + convert to bf16
        gather_bf16<<<(MT * 40 + 255) / 256, 256, 0, stream>>>(
            title_ids + (long long)c0 * 30, word_table, AbufT, MT);
        gather_bf16<<<(ME * 40 + 255) / 256, 256, 0, stream>>>(
            entity_ids + (long long)c0 * 10, entity_table, AbufE, ME);
        // 2b. projections: N=1800 (15 tiles), K=320 (10 iters), out stride 1920
        gemm_mfma2<0, 0, 0><<<dim3(15, MT / 128), 256, 0, stream>>>(
            AbufT, 320, wcatT, 320, nullptr, Tproj, NPROJ, 10, 1800);
        gemm_mfma2<0, 0, 0><<<dim3(15, ME / 128), 256, 0, stream>>>(
            AbufE, 320, wcatT, 320, nullptr, Eproj, NPROJ, 10, 1800);
        // 3. attention (self + co) -> Tcat/Ecat stride 608
        attn_title<<<C, 256, 0, stream>>>(Tproj, Eproj, Tcat);
        attn_entity<<<C, 256, 0, stream>>>(Tproj, Eproj, Ecat);
        // 4. fc1 / fc2: K=608 (19 iters), N=400
        gemm_mfma2<1, 0, 0><<<dim3(4, MT / 128), 256, 0, stream>>>(
            Tcat, 608, fc1Wt, 608, fc1_b, Tv, 400, 19, 400);
        gemm_mfma2<1, 0, 0><<<dim3(4, ME / 128), 256, 0, stream>>>(
            Ecat, 608, fc2Wt, 608, fc2_b, Ev, 400, 19, 400);
        // 5. pooling score: P = tanh(x @ W1 + b1), K=416 (13 iters), N=200
        gemm_mfma2<1, 1, 0><<<dim3(2, MT / 128), 256, 0, stream>>>(
            Tv, 400, aptWt, 416, apt_b1, Pt, 200, 13, 200);
        gemm_mfma2<1, 1, 0><<<dim3(2, ME / 128), 256, 0, stream>>>(
            Ev, 400, apeWt, 416, ape_b1, Pe, 200, 13, 200);
        // 6. pooling finalize -> bf16 into Acat cols [0,400) and [400,800)
        pool_finalize<30><<<C, 256, 0, stream>>>(Pt, Tv, apt_w2, Acat + (long long)c0 * 1024);
        pool_finalize<10><<<C, 256, 0, stream>>>(Pe, Ev, ape_w2, Acat + (long long)c0 * 1024 + 400);
    }
    // 7. fc3 (MFMA, f32 out): out[4096,400] = Acat[4096,1024] @ fc3Wt^T + b
    gemm_mfma2<1, 0, 1><<<dim3(4, BATCH / 128), 256, 0, stream>>>(
        Acat, 1024, fc3Wt, 1024, fc3_b, d_out, 400, 32, 400);
}